// Round 11
// baseline (588.786 us; speedup 1.0000x reference)
//
#include <hip/hip_runtime.h>
#include <hip/hip_fp16.h>
#include <cstdint>
#include <cstddef>

// ---------------------------------------------------------------------------
// GraphToGraph: edge-MLP scoring -> normalized spmm x5 -> directed min-label
// propagation -> group compaction -> group means.
// N=50000, E=400000, CON=128, STR=64, HID=128.
// Round-11 discipline: isolate the round-10 crash. k_edge REVERTED to the
// round-9 known-good single-edge ballot form. k_proj register-only version
// kept (LDS pipe was its 92us bottleneck). k_spmm 2-way unroll kept (safe).
// ---------------------------------------------------------------------------

// init: assemble F0 = [con | struc] (N x 192, fp16), per-node scalars
__global__ void k_init(const float* __restrict__ con, const float* __restrict__ str,
                       __half* __restrict__ F, float* __restrict__ sums,
                       int* __restrict__ cnt, int* __restrict__ g, int N) {
  int i = blockIdx.x * blockDim.x + threadIdx.x;
  int total = N * 192;
  if (i < total) {
    int n = i / 192, f = i - n * 192;
    float v = (f < 128) ? con[n * 128 + f] : str[n * 64 + (f - 128)];
    F[i] = __float2half_rn(v);
  }
  if (i < N) { sums[i] = 1.0f; cnt[i] = 1; g[i] = i; }
}

// per-node projection, register-only (no LDS):
// P[n][j] = sum_k con[n][k]*W1[k*128+j] + b1[j]; Q[n][j] = sum_k con[n][k]*W1q[k*128+j]
// Wave owns 8 nodes; lane l owns cols {l, 64+l} of both P and Q. con reads
// are wave-uniform float4 broadcasts; W1 reads lane-coalesced (L2-resident).
__global__ __launch_bounds__(256) void k_proj(const float* __restrict__ con,
                                              const float* __restrict__ W1,
                                              const float* __restrict__ b1,
                                              float* __restrict__ PQf,
                                              __half* __restrict__ PQh, int N) {
  int wave = threadIdx.x >> 6;
  int lane = threadIdx.x & 63;
  int n0 = blockIdx.x * 32 + wave * 8;
  const float* W1q = W1 + 128 * 128;
  float aP0[8], aP1[8], aQ0[8], aQ1[8];
#pragma unroll
  for (int t = 0; t < 8; ++t) { aP0[t] = 0.f; aP1[t] = 0.f; aQ0[t] = 0.f; aQ1[t] = 0.f; }
  int cL = lane, cH = 64 + lane;
  for (int k = 0; k < 128; k += 4) {
    float wP0[4], wP1[4], wQ0[4], wQ1[4];
#pragma unroll
    for (int u = 0; u < 4; ++u) {
      wP0[u] = W1[(k + u) * 128 + cL];
      wP1[u] = W1[(k + u) * 128 + cH];
      wQ0[u] = W1q[(k + u) * 128 + cL];
      wQ1[u] = W1q[(k + u) * 128 + cH];
    }
#pragma unroll
    for (int t = 0; t < 8; ++t) {
      int node = min(n0 + t, N - 1);             // wave-uniform -> broadcast
      const float4 c4 = *(const float4*)&con[(size_t)node * 128 + k];
      aP0[t] += c4.x * wP0[0] + c4.y * wP0[1] + c4.z * wP0[2] + c4.w * wP0[3];
      aP1[t] += c4.x * wP1[0] + c4.y * wP1[1] + c4.z * wP1[2] + c4.w * wP1[3];
      aQ0[t] += c4.x * wQ0[0] + c4.y * wQ0[1] + c4.z * wQ0[2] + c4.w * wQ0[3];
      aQ1[t] += c4.x * wQ1[0] + c4.y * wQ1[1] + c4.z * wQ1[2] + c4.w * wQ1[3];
    }
  }
  float bL = b1[cL], bH = b1[cH];
#pragma unroll
  for (int t = 0; t < 8; ++t) {
    int node = n0 + t;
    if (node < N) {
      float vP0 = aP0[t] + bL, vP1 = aP1[t] + bH;
      float* rf = PQf + (size_t)node * 256;
      rf[cL] = vP0; rf[cH] = vP1;
      rf[128 + cL] = aQ0[t]; rf[128 + cH] = aQ1[t];
      __half* rh = PQh + (size_t)node * 256;
      rh[cL] = __float2half_rn(vP0); rh[cH] = __float2half_rn(vP1);
      rh[128 + cL] = __float2half_rn(aQ0[t]); rh[128 + cH] = __float2half_rn(aQ1[t]);
    }
  }
}

// edge scoring, thread-per-edge (round-9 known-good form). fp16 PQ gathers,
// |raw| < 3e-3 -> exact f32 recompute. Ballot-aggregated pos compaction.
__global__ __launch_bounds__(256) void k_edge(const int* __restrict__ src, const int* __restrict__ dst,
                                              const __half* __restrict__ PQ,
                                              const float* __restrict__ PQf,
                                              const float* __restrict__ W2,
                                              const float* __restrict__ b2,
                                              float* __restrict__ scores,
                                              float* __restrict__ sums, int* __restrict__ cnt,
                                              int* __restrict__ pos_s, int* __restrict__ pos_d,
                                              int* __restrict__ pos_cnt, int E) {
  int e = blockIdx.x * 256 + threadIdx.x;
  bool live = (e < E);
  int s = 0, d = 0;
  if (live) { s = src[e]; d = dst[e]; }
  bool scored = live && (d > s);
  float raw = -1.0f;
  if (scored) {
    const uint4* P = (const uint4*)(PQ + (size_t)s * 256);
    const uint4* Q = (const uint4*)(PQ + (size_t)d * 256 + 128);
    const float4* W = (const float4*)W2;
    float acc = 0.0f;
#pragma unroll 8
    for (int k = 0; k < 16; ++k) {
      uint4 pu = P[k];
      uint4 qu = Q[k];
      float4 wa = W[2 * k], wb = W[2 * k + 1];
      float2 p0 = __half22float2(*(const __half2*)&pu.x);
      float2 p1 = __half22float2(*(const __half2*)&pu.y);
      float2 p2 = __half22float2(*(const __half2*)&pu.z);
      float2 p3 = __half22float2(*(const __half2*)&pu.w);
      float2 q0 = __half22float2(*(const __half2*)&qu.x);
      float2 q1 = __half22float2(*(const __half2*)&qu.y);
      float2 q2 = __half22float2(*(const __half2*)&qu.z);
      float2 q3 = __half22float2(*(const __half2*)&qu.w);
      acc += fmaxf(p0.x + q0.x, 0.f) * wa.x + fmaxf(p0.y + q0.y, 0.f) * wa.y
           + fmaxf(p1.x + q1.x, 0.f) * wa.z + fmaxf(p1.y + q1.y, 0.f) * wa.w
           + fmaxf(p2.x + q2.x, 0.f) * wb.x + fmaxf(p2.y + q2.y, 0.f) * wb.y
           + fmaxf(p3.x + q3.x, 0.f) * wb.z + fmaxf(p3.y + q3.y, 0.f) * wb.w;
    }
    raw = acc + b2[0];
    if (fabsf(raw) < 3e-3f) {   // borderline: exact f32 recompute (rare)
      const float4* Pf = (const float4*)(PQf + (size_t)s * 256);
      const float4* Qf = (const float4*)(PQf + (size_t)d * 256 + 128);
      float acc2 = 0.0f;
      for (int k = 0; k < 32; ++k) {
        float4 p = Pf[k], q = Qf[k], w = W[k];
        acc2 += fmaxf(p.x + q.x, 0.f) * w.x + fmaxf(p.y + q.y, 0.f) * w.y
              + fmaxf(p.z + q.z, 0.f) * w.z + fmaxf(p.w + q.w, 0.f) * w.w;
      }
      raw = acc2 + b2[0];
    }
  }
  float sc = scored ? fmaxf(raw, 0.0f) : 0.0f;
  if (live) scores[e] = sc;
  bool pos = scored && (sc > 0.0f);
  if (pos) {
    atomicAdd(&sums[s], sc);
    atomicAdd(&sums[d], sc);
    atomicAdd(&cnt[s], 1);
    atomicAdd(&cnt[d], 1);
  }
  // wave-aggregated compaction: one pos_cnt atomic per wave
  unsigned long long m = __ballot(pos);
  if (pos) {
    int lane = threadIdx.x & 63;
    int rank = __popcll(m & ((1ULL << lane) - 1));
    int leader = __ffsll((long long)m) - 1;
    int bcast;
    if (lane == leader) bcast = atomicAdd(pos_cnt, __popcll(m));
    bcast = __shfl(bcast, leader, 64);
    pos_s[bcast + rank] = s;
    pos_d[bcast + rank] = d;
  }
}

__device__ __forceinline__ int wave_iscan(int v) {
  int l = threadIdx.x & 63;
#pragma unroll
  for (int o = 1; o < 64; o <<= 1) {
    int t = __shfl_up(v, o, 64);
    if (l >= o) v += t;
  }
  return v;
}

// ---- 3-phase multi-block exclusive scan over N elements ----
__global__ __launch_bounds__(1024) void k_scan_red(int mode, const int* __restrict__ cnt,
                                                   const int* __restrict__ g,
                                                   int* __restrict__ bsum, int N) {
  __shared__ int wsum[16];
  int i = blockIdx.x * 1024 + threadIdx.x;
  int v = 0;
  if (i < N) v = (mode == 0) ? cnt[i] : ((g[i] == i) ? 1 : 0);
  int incl = wave_iscan(v);
  int wid = threadIdx.x >> 6;
  if ((threadIdx.x & 63) == 63) wsum[wid] = incl;
  __syncthreads();
  if (threadIdx.x == 0) {
    int t = 0;
#pragma unroll
    for (int k = 0; k < 16; ++k) t += wsum[k];
    bsum[blockIdx.x] = t;
  }
}

__global__ __launch_bounds__(64) void k_scan_mid(int mode, const int* __restrict__ bsum,
                                                 int* __restrict__ bexcl, int NB,
                                                 int* __restrict__ rowp, int N) {
  int l = threadIdx.x;
  int v = (l < NB) ? bsum[l] : 0;
  int incl = wave_iscan(v);
  if (l < NB) bexcl[l] = incl - v;
  if (l == 63 && mode == 0) rowp[N] = incl;   // grand total
}

__global__ __launch_bounds__(1024) void k_scan_out(int mode, const int* __restrict__ cnt,
                                                   const int* __restrict__ g,
                                                   const float* __restrict__ sums,
                                                   const int* __restrict__ bexcl,
                                                   int* __restrict__ rowp, int* __restrict__ fillp,
                                                   int* __restrict__ col, float* __restrict__ wt,
                                                   int* __restrict__ rank, int N) {
  __shared__ int wsum[16];
  int i = blockIdx.x * 1024 + threadIdx.x;
  int v = 0;
  if (i < N) v = (mode == 0) ? cnt[i] : ((g[i] == i) ? 1 : 0);
  int incl = wave_iscan(v);
  int wid = threadIdx.x >> 6;
  if ((threadIdx.x & 63) == 63) wsum[wid] = incl;
  __syncthreads();
  if (threadIdx.x < 64) {
    int l = threadIdx.x;
    int sv = (l < 16) ? wsum[l] : 0;
#pragma unroll
    for (int o = 1; o < 16; o <<= 1) {
      int t = __shfl_up(sv, o, 64);
      if (l >= o) sv += t;
    }
    if (l < 16) wsum[l] = sv;
  }
  __syncthreads();
  int wexcl = (wid == 0) ? 0 : wsum[wid - 1];
  int excl = bexcl[blockIdx.x] + wexcl + incl - v;
  if (i < N) {
    if (mode == 0) {
      rowp[i] = excl;
      fillp[i] = excl + 1;       // slot 0 of each row = self loop
      col[excl] = i;
      wt[excl] = 1.0f / sums[i];
    } else {
      rank[i] = excl;
    }
  }
}

// scatter positive edges (both directions) into CSR with normalized weights
__global__ void k_fill(const int* __restrict__ src, const int* __restrict__ dst,
                       const float* __restrict__ scores, const float* __restrict__ sums,
                       int* __restrict__ fillp, int* __restrict__ col, float* __restrict__ wt,
                       int E) {
  int e = blockIdx.x * blockDim.x + threadIdx.x;
  if (e >= E) return;
  float sc = scores[e];
  if (sc <= 0.0f) return;
  int s = src[e], d = dst[e];
  int p = atomicAdd(&fillp[s], 1);
  col[p] = d; wt[p] = sc / sums[s];
  int p2 = atomicAdd(&fillp[d], 1);
  col[p2] = s; wt[p2] = sc / sums[d];
}

// spmm over fp16 features: thread-per-(row, 8 halves), 2-way entry unroll
// (both gathers in flight before consumption).
__global__ __launch_bounds__(192) void k_spmm(const __half* __restrict__ Fin, __half* __restrict__ Fout,
                                              const int* __restrict__ rowp,
                                              const int* __restrict__ col,
                                              const float* __restrict__ wt, int N) {
  int tid = blockIdx.x * 192 + threadIdx.x;
  int row = tid / 24;
  int f8 = tid - row * 24;
  if (row >= N) return;
  const uint4* F8 = (const uint4*)Fin;
  int beg = rowp[row], end = rowp[row + 1];
  float a0 = 0.f, a1 = 0.f, a2 = 0.f, a3 = 0.f, a4 = 0.f, a5 = 0.f, a6 = 0.f, a7 = 0.f;
  int idx = beg;
  for (; idx + 1 < end; idx += 2) {
    int c0 = col[idx], c1 = col[idx + 1];
    float w0 = wt[idx], w1 = wt[idx + 1];
    uint4 u0 = F8[(size_t)c0 * 24 + f8];
    uint4 u1 = F8[(size_t)c1 * 24 + f8];
    float2 x0 = __half22float2(*(const __half2*)&u0.x);
    float2 x1 = __half22float2(*(const __half2*)&u0.y);
    float2 x2 = __half22float2(*(const __half2*)&u0.z);
    float2 x3 = __half22float2(*(const __half2*)&u0.w);
    a0 += w0 * x0.x; a1 += w0 * x0.y; a2 += w0 * x1.x; a3 += w0 * x1.y;
    a4 += w0 * x2.x; a5 += w0 * x2.y; a6 += w0 * x3.x; a7 += w0 * x3.y;
    float2 y0 = __half22float2(*(const __half2*)&u1.x);
    float2 y1 = __half22float2(*(const __half2*)&u1.y);
    float2 y2 = __half22float2(*(const __half2*)&u1.z);
    float2 y3 = __half22float2(*(const __half2*)&u1.w);
    a0 += w1 * y0.x; a1 += w1 * y0.y; a2 += w1 * y1.x; a3 += w1 * y1.y;
    a4 += w1 * y2.x; a5 += w1 * y2.y; a6 += w1 * y3.x; a7 += w1 * y3.y;
  }
  if (idx < end) {
    int c0 = col[idx];
    float w0 = wt[idx];
    uint4 u0 = F8[(size_t)c0 * 24 + f8];
    float2 x0 = __half22float2(*(const __half2*)&u0.x);
    float2 x1 = __half22float2(*(const __half2*)&u0.y);
    float2 x2 = __half22float2(*(const __half2*)&u0.z);
    float2 x3 = __half22float2(*(const __half2*)&u0.w);
    a0 += w0 * x0.x; a1 += w0 * x0.y; a2 += w0 * x1.x; a3 += w0 * x1.y;
    a4 += w0 * x2.x; a5 += w0 * x2.y; a6 += w0 * x3.x; a7 += w0 * x3.y;
  }
  uint4 o;
  *(__half2*)&o.x = __floats2half2_rn(a0, a1);
  *(__half2*)&o.y = __floats2half2_rn(a2, a3);
  *(__half2*)&o.z = __floats2half2_rn(a4, a5);
  *(__half2*)&o.w = __floats2half2_rn(a6, a7);
  ((uint4*)Fout)[(size_t)row * 24 + f8] = o;
}

// directed min-label propagation: edge sweeps + sound label-jumping.
__global__ void k_prop(const int* __restrict__ pos_s, const int* __restrict__ pos_d,
                       const int* __restrict__ pos_cnt, int* g, int N) {
  int i = blockIdx.x * blockDim.x + threadIdx.x;
  volatile int* gv = g;
  int P = *pos_cnt;
#pragma unroll
  for (int r = 0; r < 2; ++r) {
    if (i < P) {
      int s = pos_s[i], d = pos_d[i];
      int gs = gv[s];
      if (gs < gv[d]) atomicMin(&g[d], gs);
    }
    if (i < N) {
      int gi = gv[i];
      int gg = gv[gi];
      if (gg < gi) atomicMin(&g[i], gg);
      gi = gv[i];
      gg = gv[gi];
      if (gg < gi) atomicMin(&g[i], gg);
    }
  }
}

// per-group member counts (gcnt zeroed beforehand)
__global__ void k_gcnt(const int* __restrict__ g, const int* __restrict__ rank,
                       int* __restrict__ gcnt, int N) {
  int i = blockIdx.x * blockDim.x + threadIdx.x;
  if (i < N) atomicAdd(&gcnt[rank[g[i]]], 1);
}

// per-group inverse count
__global__ void k_inv(const int* __restrict__ gcnt, float* __restrict__ invc, int N) {
  int i = blockIdx.x * blockDim.x + threadIdx.x;
  if (i < N) invc[i] = 1.0f / (float)max(gcnt[i], 1);
}

// group mean accumulation: 64-node chunk per block, run-length coalesced
// atomics, mean fused via invc scale at run flush. F is fp16, out f32.
__global__ __launch_bounds__(192) void k_accum(const __half* __restrict__ F, const int* __restrict__ g,
                                               const int* __restrict__ rank,
                                               const float* __restrict__ invc,
                                               float* __restrict__ out, int N) {
  __shared__ int jbuf[64];
  int n0 = blockIdx.x * 64;
  if (threadIdx.x < 64) {
    int n = n0 + threadIdx.x;
    jbuf[threadIdx.x] = (n < N) ? rank[g[n]] : -1;
  }
  __syncthreads();
  int f = threadIdx.x;
  int lim = min(64, N - n0);
  float acc = 0.0f; int cur = -1;
  for (int k = 0; k < lim; ++k) {
    int j = jbuf[k];
    float v = __half2float(F[(size_t)(n0 + k) * 192 + f]);
    if (j != cur) {
      if (cur >= 0) atomicAdd(&out[(size_t)cur * 192 + f], acc * invc[cur]);
      cur = j; acc = v;
    } else {
      acc += v;
    }
  }
  if (cur >= 0) atomicAdd(&out[(size_t)cur * 192 + f], acc * invc[cur]);
}

extern "C" void kernel_launch(void* const* d_in, const int* in_sizes, int n_in,
                              void* d_out, int out_size, void* d_ws, size_t ws_size,
                              hipStream_t stream) {
  const float* con = (const float*)d_in[0];
  const float* str = (const float*)d_in[1];
  const float* W1  = (const float*)d_in[2];
  const float* b1  = (const float*)d_in[3];
  const float* W2  = (const float*)d_in[4];
  const float* b2  = (const float*)d_in[5];
  const int* edges = (const int*)d_in[6];
  int N = in_sizes[0] / 128;
  int E = in_sizes[6] / 2;
  const int* src = edges;
  const int* dst = edges + E;
  int NB = (N + 1023) / 1024;   // scan blocks (<=64)

  uint8_t* w = (uint8_t*)d_ws;
  size_t off = 0;
  auto alloc = [&](size_t bytes) -> void* {
    void* p = w + off;
    off += (bytes + 255) & ~(size_t)255;
    return p;
  };
  // Live-range aliasing:
  //  - Fb (fp16 feature ping buffer) aliases PQf (dead after k_edge).
  //  - PQh (fp16 PQ, dead after k_edge) overlaps the CSR/compaction arrays.
  __half* Fa    = (__half*)alloc((size_t)N * 192 * 2);
  float*  PQf   = (float*)alloc((size_t)N * 256 * 4);
  __half* Fb    = (__half*)PQf;
  float* scores = (float*)alloc((size_t)E * 4);
  float* sums   = (float*)alloc((size_t)N * 4);
  int*   cnt    = (int*)alloc((size_t)N * 4);
  int*   g      = (int*)alloc((size_t)N * 4);
  int*   pos_s  = (int*)alloc((size_t)E * 4);
  int*   pos_d  = (int*)alloc((size_t)E * 4);
  int*   pos_c  = (int*)alloc(256);
  int*   bsum   = (int*)alloc(64 * 4);
  int*   bexcl  = (int*)alloc(64 * 4);
  size_t mark = off;                       // overlap region start
  int*   colA   = (int*)alloc((2 * (size_t)E + N) * 4);
  float* wtA    = (float*)alloc((2 * (size_t)E + N) * 4);
  int*   rowp   = (int*)alloc((size_t)(N + 1) * 4);
  int*   fillp  = (int*)alloc((size_t)N * 4);
  int*   rank   = (int*)alloc((size_t)N * 4);
  int*   gcnt   = (int*)alloc((size_t)N * 4);
  float* invc   = (float*)alloc((size_t)N * 4);
  size_t pqh_bytes = (size_t)N * 256 * 2;
  if (off < mark + pqh_bytes) off = mark + ((pqh_bytes + 255) & ~(size_t)255);
  __half* PQh = (__half*)(w + mark);

  hipMemsetAsync(d_out, 0, (size_t)out_size * 4, stream);
  hipMemsetAsync(pos_c, 0, 4, stream);

  k_init<<<(N * 192 + 255) / 256, 256, 0, stream>>>(con, str, Fa, sums, cnt, g, N);
  k_proj<<<(N + 31) / 32, 256, 0, stream>>>(con, W1, b1, PQf, PQh, N);
  k_edge<<<(E + 255) / 256, 256, 0, stream>>>(src, dst, PQh, PQf, W2, b2, scores, sums, cnt,
                                              pos_s, pos_d, pos_c, E);
  // PQh dead from here; overlap region becomes CSR/compaction storage.
  k_scan_red<<<NB, 1024, 0, stream>>>(0, cnt, g, bsum, N);
  k_scan_mid<<<1, 64, 0, stream>>>(0, bsum, bexcl, NB, rowp, N);
  k_scan_out<<<NB, 1024, 0, stream>>>(0, cnt, g, sums, bexcl, rowp, fillp, colA, wtA, rank, N);
  k_fill<<<(E + 255) / 256, 256, 0, stream>>>(src, dst, scores, sums, fillp, colA, wtA, E);

  __half* fin = Fa; __half* fout = Fb;
  for (int it = 0; it < 5; ++it) {
    k_spmm<<<((size_t)N * 24 + 191) / 192, 192, 0, stream>>>(fin, fout, rowp, colA, wtA, N);
    __half* tmp = fin; fin = fout; fout = tmp;
  }

  for (int r = 0; r < 9; ++r)
    k_prop<<<(E + 255) / 256, 256, 0, stream>>>(pos_s, pos_d, pos_c, g, N);

  k_scan_red<<<NB, 1024, 0, stream>>>(1, cnt, g, bsum, N);
  k_scan_mid<<<1, 64, 0, stream>>>(1, bsum, bexcl, NB, rowp, N);
  k_scan_out<<<NB, 1024, 0, stream>>>(1, cnt, g, sums, bexcl, rowp, fillp, colA, wtA, rank, N);
  hipMemsetAsync(gcnt, 0, (size_t)N * 4, stream);
  k_gcnt<<<(N + 255) / 256, 256, 0, stream>>>(g, rank, gcnt, N);
  k_inv<<<(N + 255) / 256, 256, 0, stream>>>(gcnt, invc, N);
  k_accum<<<(N + 63) / 64, 192, 0, stream>>>(fin, g, rank, invc, (float*)d_out, N);
}

// Round 13
// 587.154 us; speedup vs baseline: 1.0028x; 1.0028x over previous
//
#include <hip/hip_runtime.h>
#include <hip/hip_fp16.h>
#include <cstdint>
#include <cstddef>

// ---------------------------------------------------------------------------
// GraphToGraph: edge-MLP scoring -> normalized spmm x5 -> directed min-label
// propagation -> group compaction -> group means.
// N=50000, E=400000, CON=128, STR=64, HID=128.
// k_projm: f16 MFMA GEMM (f32 accum) for the per-node projection — replaces
//   the 92us VALU GEMM (3.3 GFLOP -> matrix pipe). No PQf: borderline edges
//   (|raw|<1e-2) are exactly recomputed in f32 by k_border (1 wave/edge),
//   keeping connectivity sign decisions f32-exact.
// k_edge: round-9 known-good thread-per-edge + ballot compaction.
// ---------------------------------------------------------------------------

typedef _Float16 f16x8 __attribute__((ext_vector_type(8)));
typedef float f32x4 __attribute__((ext_vector_type(4)));

// init: assemble F0 = [con | struc] (N x 192, fp16), per-node scalars
__global__ void k_init(const float* __restrict__ con, const float* __restrict__ str,
                       __half* __restrict__ F, float* __restrict__ sums,
                       int* __restrict__ cnt, int* __restrict__ g, int N) {
  int i = blockIdx.x * blockDim.x + threadIdx.x;
  int total = N * 192;
  if (i < total) {
    int n = i / 192, f = i - n * 192;
    float v = (f < 128) ? con[n * 128 + f] : str[n * 64 + (f - 128)];
    F[i] = __float2half_rn(v);
  }
  if (i < N) { sums[i] = 1.0f; cnt[i] = 1; g[i] = i; }
}

// W1 -> fp16, transposed+fused halves: BT[c][k] = W1_top[k][c] (c<128)
//                                              = W1_bot[k][c-128] (c>=128)
__global__ void k_wprep(const float* __restrict__ W1, __half* __restrict__ BT) {
  int i = blockIdx.x * 256 + threadIdx.x;
  if (i < 256 * 128) {
    int c = i >> 7, k = i & 127;
    float v = (c < 128) ? W1[k * 128 + c] : W1[16384 + k * 128 + (c - 128)];
    BT[(size_t)c * 128 + k] = __float2half_rn(v);
  }
}

// per-node projection via MFMA f32_16x16x32_f16 (f32 accumulate).
// Block = 16 nodes x 256 cols; 4 waves x 4 N-tiles each. A from Fa (fp16 con,
// row stride 192), B from BT. C/D layout (HW-verified): col=lane&15,
// row=(lane>>4)*4+reg. Bias b1 added to P cols (col<128).
__global__ __launch_bounds__(256) void k_projm(const __half* __restrict__ Fa,
                                               const __half* __restrict__ BT,
                                               const float* __restrict__ b1,
                                               __half* __restrict__ PQh, int N) {
  int wave = threadIdx.x >> 6, lane = threadIdx.x & 63;
  int m0 = blockIdx.x * 16;
  int r16 = lane & 15, grp = lane >> 4;
  const _Float16* A = (const _Float16*)Fa;
  const _Float16* B = (const _Float16*)BT;
  int node = m0 + r16; if (node >= N) node = N - 1;
  f16x8 afr[4];
#pragma unroll
  for (int ks = 0; ks < 4; ++ks)
    afr[ks] = *(const f16x8*)(A + (size_t)node * 192 + ks * 32 + grp * 8);
#pragma unroll
  for (int nt = 0; nt < 4; ++nt) {
    int col = (wave * 4 + nt) * 16 + r16;
    f32x4 acc = {0.f, 0.f, 0.f, 0.f};
#pragma unroll
    for (int ks = 0; ks < 4; ++ks) {
      f16x8 bfr = *(const f16x8*)(B + (size_t)col * 128 + ks * 32 + grp * 8);
      acc = __builtin_amdgcn_mfma_f32_16x16x32_f16(afr[ks], bfr, acc, 0, 0, 0);
    }
    float bias = (col < 128) ? b1[col] : 0.0f;
#pragma unroll
    for (int r = 0; r < 4; ++r) {
      int nrow = m0 + grp * 4 + r;
      if (nrow < N) PQh[(size_t)nrow * 256 + col] = __float2half_rn(acc[r] + bias);
    }
  }
}

// edge scoring, thread-per-edge over fp16 PQ. |raw| < 1e-2 -> deferred to
// k_border (exact f32). Ballot-aggregated compaction for pos AND border lists.
__global__ __launch_bounds__(256) void k_edge(const int* __restrict__ src, const int* __restrict__ dst,
                                              const __half* __restrict__ PQ,
                                              const float* __restrict__ W2,
                                              const float* __restrict__ b2,
                                              float* __restrict__ scores,
                                              float* __restrict__ sums, int* __restrict__ cnt,
                                              int* __restrict__ pos_s, int* __restrict__ pos_d,
                                              int* __restrict__ pos_cnt,
                                              int* __restrict__ bord, int* __restrict__ bord_cnt,
                                              int E) {
  int e = blockIdx.x * 256 + threadIdx.x;
  bool live = (e < E);
  int s = 0, d = 0;
  if (live) { s = src[e]; d = dst[e]; }
  bool scored = live && (d > s);
  float raw = -1.0f;
  if (scored) {
    const uint4* P = (const uint4*)(PQ + (size_t)s * 256);
    const uint4* Q = (const uint4*)(PQ + (size_t)d * 256 + 128);
    const float4* W = (const float4*)W2;
    float acc = 0.0f;
#pragma unroll 8
    for (int k = 0; k < 16; ++k) {
      uint4 pu = P[k];
      uint4 qu = Q[k];
      float4 wa = W[2 * k], wb = W[2 * k + 1];
      float2 p0 = __half22float2(*(const __half2*)&pu.x);
      float2 p1 = __half22float2(*(const __half2*)&pu.y);
      float2 p2 = __half22float2(*(const __half2*)&pu.z);
      float2 p3 = __half22float2(*(const __half2*)&pu.w);
      float2 q0 = __half22float2(*(const __half2*)&qu.x);
      float2 q1 = __half22float2(*(const __half2*)&qu.y);
      float2 q2 = __half22float2(*(const __half2*)&qu.z);
      float2 q3 = __half22float2(*(const __half2*)&qu.w);
      acc += fmaxf(p0.x + q0.x, 0.f) * wa.x + fmaxf(p0.y + q0.y, 0.f) * wa.y
           + fmaxf(p1.x + q1.x, 0.f) * wa.z + fmaxf(p1.y + q1.y, 0.f) * wa.w
           + fmaxf(p2.x + q2.x, 0.f) * wb.x + fmaxf(p2.y + q2.y, 0.f) * wb.y
           + fmaxf(p3.x + q3.x, 0.f) * wb.z + fmaxf(p3.y + q3.y, 0.f) * wb.w;
    }
    raw = acc + b2[0];
  }
  bool border = scored && (fabsf(raw) < 1e-2f);
  bool fin = scored && !border;
  float sc = fin ? fmaxf(raw, 0.0f) : 0.0f;
  if (live && !border) scores[e] = sc;     // border edges written by k_border
  bool pos = fin && (sc > 0.0f);
  if (pos) {
    atomicAdd(&sums[s], sc);
    atomicAdd(&sums[d], sc);
    atomicAdd(&cnt[s], 1);
    atomicAdd(&cnt[d], 1);
  }
  int lane = threadIdx.x & 63;
  {
    unsigned long long m = __ballot(pos);
    if (pos) {
      int rank = __popcll(m & ((1ULL << lane) - 1));
      int leader = __ffsll((long long)m) - 1;
      int bcast;
      if (lane == leader) bcast = atomicAdd(pos_cnt, __popcll(m));
      bcast = __shfl(bcast, leader, 64);
      pos_s[bcast + rank] = s;
      pos_d[bcast + rank] = d;
    }
  }
  {
    unsigned long long m = __ballot(border);
    if (border) {
      int rank = __popcll(m & ((1ULL << lane) - 1));
      int leader = __ffsll((long long)m) - 1;
      int bcast;
      if (lane == leader) bcast = atomicAdd(bord_cnt, __popcll(m));
      bcast = __shfl(bcast, leader, 64);
      bord[bcast + rank] = e;
    }
  }
}

// exact f32 rescore of borderline edges: one wave per edge. Lane owns hidden
// cols {lane, lane+64}; con reads wave-uniform broadcast, W1 reads coalesced.
__global__ __launch_bounds__(256) void k_border(const int* __restrict__ src, const int* __restrict__ dst,
                                                const float* __restrict__ con,
                                                const float* __restrict__ W1,
                                                const float* __restrict__ b1,
                                                const float* __restrict__ W2,
                                                const float* __restrict__ b2,
                                                const int* __restrict__ bord,
                                                const int* __restrict__ bord_cnt,
                                                float* __restrict__ scores,
                                                float* __restrict__ sums, int* __restrict__ cnt,
                                                int* __restrict__ pos_s, int* __restrict__ pos_d,
                                                int* __restrict__ pos_cnt) {
  int nb = *bord_cnt;
  int lane = threadIdx.x & 63;
  int wid = (blockIdx.x * 256 + threadIdx.x) >> 6;
  int nwaves = (gridDim.x * 256) >> 6;
  const float* W1q = W1 + 128 * 128;
  int j0 = lane, j1 = lane + 64;
  float b1v0 = b1[j0], b1v1 = b1[j1];
  float w2v0 = W2[j0], w2v1 = W2[j1];
  for (int w = wid; w < nb; w += nwaves) {
    int e = bord[w];
    int s = src[e], d = dst[e];
    const float* cs = con + (size_t)s * 128;
    const float* cd = con + (size_t)d * 128;
    float h0 = 0.f, h1 = 0.f;
    for (int k = 0; k < 128; ++k) {
      float a = cs[k], b = cd[k];               // wave-uniform broadcasts
      h0 += a * W1[k * 128 + j0] + b * W1q[k * 128 + j0];
      h1 += a * W1[k * 128 + j1] + b * W1q[k * 128 + j1];
    }
    float v = fmaxf(h0 + b1v0, 0.f) * w2v0 + fmaxf(h1 + b1v1, 0.f) * w2v1;
#pragma unroll
    for (int o = 32; o > 0; o >>= 1) v += __shfl_xor(v, o, 64);
    if (lane == 0) {
      float sc = fmaxf(v + b2[0], 0.0f);
      scores[e] = sc;
      if (sc > 0.0f) {
        atomicAdd(&sums[s], sc);
        atomicAdd(&sums[d], sc);
        atomicAdd(&cnt[s], 1);
        atomicAdd(&cnt[d], 1);
        int p = atomicAdd(pos_cnt, 1);
        pos_s[p] = s; pos_d[p] = d;
      }
    }
  }
}

__device__ __forceinline__ int wave_iscan(int v) {
  int l = threadIdx.x & 63;
#pragma unroll
  for (int o = 1; o < 64; o <<= 1) {
    int t = __shfl_up(v, o, 64);
    if (l >= o) v += t;
  }
  return v;
}

// ---- 3-phase multi-block exclusive scan over N elements ----
__global__ __launch_bounds__(1024) void k_scan_red(int mode, const int* __restrict__ cnt,
                                                   const int* __restrict__ g,
                                                   int* __restrict__ bsum, int N) {
  __shared__ int wsum[16];
  int i = blockIdx.x * 1024 + threadIdx.x;
  int v = 0;
  if (i < N) v = (mode == 0) ? cnt[i] : ((g[i] == i) ? 1 : 0);
  int incl = wave_iscan(v);
  int wid = threadIdx.x >> 6;
  if ((threadIdx.x & 63) == 63) wsum[wid] = incl;
  __syncthreads();
  if (threadIdx.x == 0) {
    int t = 0;
#pragma unroll
    for (int k = 0; k < 16; ++k) t += wsum[k];
    bsum[blockIdx.x] = t;
  }
}

__global__ __launch_bounds__(64) void k_scan_mid(int mode, const int* __restrict__ bsum,
                                                 int* __restrict__ bexcl, int NB,
                                                 int* __restrict__ rowp, int N) {
  int l = threadIdx.x;
  int v = (l < NB) ? bsum[l] : 0;
  int incl = wave_iscan(v);
  if (l < NB) bexcl[l] = incl - v;
  if (l == 63 && mode == 0) rowp[N] = incl;   // grand total
}

__global__ __launch_bounds__(1024) void k_scan_out(int mode, const int* __restrict__ cnt,
                                                   const int* __restrict__ g,
                                                   const float* __restrict__ sums,
                                                   const int* __restrict__ bexcl,
                                                   int* __restrict__ rowp, int* __restrict__ fillp,
                                                   int* __restrict__ col, float* __restrict__ wt,
                                                   int* __restrict__ rank, int N) {
  __shared__ int wsum[16];
  int i = blockIdx.x * 1024 + threadIdx.x;
  int v = 0;
  if (i < N) v = (mode == 0) ? cnt[i] : ((g[i] == i) ? 1 : 0);
  int incl = wave_iscan(v);
  int wid = threadIdx.x >> 6;
  if ((threadIdx.x & 63) == 63) wsum[wid] = incl;
  __syncthreads();
  if (threadIdx.x < 64) {
    int l = threadIdx.x;
    int sv = (l < 16) ? wsum[l] : 0;
#pragma unroll
    for (int o = 1; o < 16; o <<= 1) {
      int t = __shfl_up(sv, o, 64);
      if (l >= o) sv += t;
    }
    if (l < 16) wsum[l] = sv;
  }
  __syncthreads();
  int wexcl = (wid == 0) ? 0 : wsum[wid - 1];
  int excl = bexcl[blockIdx.x] + wexcl + incl - v;
  if (i < N) {
    if (mode == 0) {
      rowp[i] = excl;
      fillp[i] = excl + 1;       // slot 0 of each row = self loop
      col[excl] = i;
      wt[excl] = 1.0f / sums[i];
    } else {
      rank[i] = excl;
    }
  }
}

// scatter positive edges (both directions) into CSR with normalized weights
__global__ void k_fill(const int* __restrict__ src, const int* __restrict__ dst,
                       const float* __restrict__ scores, const float* __restrict__ sums,
                       int* __restrict__ fillp, int* __restrict__ col, float* __restrict__ wt,
                       int E) {
  int e = blockIdx.x * blockDim.x + threadIdx.x;
  if (e >= E) return;
  float sc = scores[e];
  if (sc <= 0.0f) return;
  int s = src[e], d = dst[e];
  int p = atomicAdd(&fillp[s], 1);
  col[p] = d; wt[p] = sc / sums[s];
  int p2 = atomicAdd(&fillp[d], 1);
  col[p2] = s; wt[p2] = sc / sums[d];
}

// spmm over fp16 features: thread-per-(row, 8 halves), 2-way entry unroll.
__global__ __launch_bounds__(192) void k_spmm(const __half* __restrict__ Fin, __half* __restrict__ Fout,
                                              const int* __restrict__ rowp,
                                              const int* __restrict__ col,
                                              const float* __restrict__ wt, int N) {
  int tid = blockIdx.x * 192 + threadIdx.x;
  int row = tid / 24;
  int f8 = tid - row * 24;
  if (row >= N) return;
  const uint4* F8 = (const uint4*)Fin;
  int beg = rowp[row], end = rowp[row + 1];
  float a0 = 0.f, a1 = 0.f, a2 = 0.f, a3 = 0.f, a4 = 0.f, a5 = 0.f, a6 = 0.f, a7 = 0.f;
  int idx = beg;
  for (; idx + 1 < end; idx += 2) {
    int c0 = col[idx], c1 = col[idx + 1];
    float w0 = wt[idx], w1 = wt[idx + 1];
    uint4 u0 = F8[(size_t)c0 * 24 + f8];
    uint4 u1 = F8[(size_t)c1 * 24 + f8];
    float2 x0 = __half22float2(*(const __half2*)&u0.x);
    float2 x1 = __half22float2(*(const __half2*)&u0.y);
    float2 x2 = __half22float2(*(const __half2*)&u0.z);
    float2 x3 = __half22float2(*(const __half2*)&u0.w);
    a0 += w0 * x0.x; a1 += w0 * x0.y; a2 += w0 * x1.x; a3 += w0 * x1.y;
    a4 += w0 * x2.x; a5 += w0 * x2.y; a6 += w0 * x3.x; a7 += w0 * x3.y;
    float2 y0 = __half22float2(*(const __half2*)&u1.x);
    float2 y1 = __half22float2(*(const __half2*)&u1.y);
    float2 y2 = __half22float2(*(const __half2*)&u1.z);
    float2 y3 = __half22float2(*(const __half2*)&u1.w);
    a0 += w1 * y0.x; a1 += w1 * y0.y; a2 += w1 * y1.x; a3 += w1 * y1.y;
    a4 += w1 * y2.x; a5 += w1 * y2.y; a6 += w1 * y3.x; a7 += w1 * y3.y;
  }
  if (idx < end) {
    int c0 = col[idx];
    float w0 = wt[idx];
    uint4 u0 = F8[(size_t)c0 * 24 + f8];
    float2 x0 = __half22float2(*(const __half2*)&u0.x);
    float2 x1 = __half22float2(*(const __half2*)&u0.y);
    float2 x2 = __half22float2(*(const __half2*)&u0.z);
    float2 x3 = __half22float2(*(const __half2*)&u0.w);
    a0 += w0 * x0.x; a1 += w0 * x0.y; a2 += w0 * x1.x; a3 += w0 * x1.y;
    a4 += w0 * x2.x; a5 += w0 * x2.y; a6 += w0 * x3.x; a7 += w0 * x3.y;
  }
  uint4 o;
  *(__half2*)&o.x = __floats2half2_rn(a0, a1);
  *(__half2*)&o.y = __floats2half2_rn(a2, a3);
  *(__half2*)&o.z = __floats2half2_rn(a4, a5);
  *(__half2*)&o.w = __floats2half2_rn(a6, a7);
  ((uint4*)Fout)[(size_t)row * 24 + f8] = o;
}

// directed min-label propagation: edge sweeps + sound label-jumping.
__global__ void k_prop(const int* __restrict__ pos_s, const int* __restrict__ pos_d,
                       const int* __restrict__ pos_cnt, int* g, int N) {
  int i = blockIdx.x * blockDim.x + threadIdx.x;
  volatile int* gv = g;
  int P = *pos_cnt;
#pragma unroll
  for (int r = 0; r < 2; ++r) {
    if (i < P) {
      int s = pos_s[i], d = pos_d[i];
      int gs = gv[s];
      if (gs < gv[d]) atomicMin(&g[d], gs);
    }
    if (i < N) {
      int gi = gv[i];
      int gg = gv[gi];
      if (gg < gi) atomicMin(&g[i], gg);
      gi = gv[i];
      gg = gv[gi];
      if (gg < gi) atomicMin(&g[i], gg);
    }
  }
}

// per-group member counts (gcnt zeroed beforehand)
__global__ void k_gcnt(const int* __restrict__ g, const int* __restrict__ rank,
                       int* __restrict__ gcnt, int N) {
  int i = blockIdx.x * blockDim.x + threadIdx.x;
  if (i < N) atomicAdd(&gcnt[rank[g[i]]], 1);
}

// per-group inverse count
__global__ void k_inv(const int* __restrict__ gcnt, float* __restrict__ invc, int N) {
  int i = blockIdx.x * blockDim.x + threadIdx.x;
  if (i < N) invc[i] = 1.0f / (float)max(gcnt[i], 1);
}

// group mean accumulation: 64-node chunk per block, run-length coalesced
// atomics, mean fused via invc scale at run flush. F is fp16, out f32.
__global__ __launch_bounds__(192) void k_accum(const __half* __restrict__ F, const int* __restrict__ g,
                                               const int* __restrict__ rank,
                                               const float* __restrict__ invc,
                                               float* __restrict__ out, int N) {
  __shared__ int jbuf[64];
  int n0 = blockIdx.x * 64;
  if (threadIdx.x < 64) {
    int n = n0 + threadIdx.x;
    jbuf[threadIdx.x] = (n < N) ? rank[g[n]] : -1;
  }
  __syncthreads();
  int f = threadIdx.x;
  int lim = min(64, N - n0);
  float acc = 0.0f; int cur = -1;
  for (int k = 0; k < lim; ++k) {
    int j = jbuf[k];
    float v = __half2float(F[(size_t)(n0 + k) * 192 + f]);
    if (j != cur) {
      if (cur >= 0) atomicAdd(&out[(size_t)cur * 192 + f], acc * invc[cur]);
      cur = j; acc = v;
    } else {
      acc += v;
    }
  }
  if (cur >= 0) atomicAdd(&out[(size_t)cur * 192 + f], acc * invc[cur]);
}

extern "C" void kernel_launch(void* const* d_in, const int* in_sizes, int n_in,
                              void* d_out, int out_size, void* d_ws, size_t ws_size,
                              hipStream_t stream) {
  const float* con = (const float*)d_in[0];
  const float* str = (const float*)d_in[1];
  const float* W1  = (const float*)d_in[2];
  const float* b1  = (const float*)d_in[3];
  const float* W2  = (const float*)d_in[4];
  const float* b2  = (const float*)d_in[5];
  const int* edges = (const int*)d_in[6];
  int N = in_sizes[0] / 128;
  int E = in_sizes[6] / 2;
  const int* src = edges;
  const int* dst = edges + E;
  int NB = (N + 1023) / 1024;   // scan blocks (<=64)

  uint8_t* w = (uint8_t*)d_ws;
  size_t off = 0;
  auto alloc = [&](size_t bytes) -> void* {
    void* p = w + off;
    off += (bytes + 255) & ~(size_t)255;
    return p;
  };
  // PQh (fp16 PQ, dead after k_edge) overlaps the CSR/compaction arrays
  // (all first written after k_edge). bord lives OUTSIDE the overlap (written
  // during k_edge).
  __half* Fa    = (__half*)alloc((size_t)N * 192 * 2);
  __half* Fb    = (__half*)alloc((size_t)N * 192 * 2);
  float* scores = (float*)alloc((size_t)E * 4);
  float* sums   = (float*)alloc((size_t)N * 4);
  int*   cnt    = (int*)alloc((size_t)N * 4);
  int*   g      = (int*)alloc((size_t)N * 4);
  int*   pos_s  = (int*)alloc((size_t)E * 4);
  int*   pos_d  = (int*)alloc((size_t)E * 4);
  int*   pos_c  = (int*)alloc(256);           // [0]=pos count, [1]=border count
  int*   bord   = (int*)alloc((size_t)E * 4);
  __half* BT    = (__half*)alloc((size_t)256 * 128 * 2);
  int*   bsum   = (int*)alloc(64 * 4);
  int*   bexcl  = (int*)alloc(64 * 4);
  size_t mark = off;                           // overlap region start
  int*   colA   = (int*)alloc((2 * (size_t)E + N) * 4);
  float* wtA    = (float*)alloc((2 * (size_t)E + N) * 4);
  int*   rowp   = (int*)alloc((size_t)(N + 1) * 4);
  int*   fillp  = (int*)alloc((size_t)N * 4);
  int*   rank   = (int*)alloc((size_t)N * 4);
  int*   gcnt   = (int*)alloc((size_t)N * 4);
  float* invc   = (float*)alloc((size_t)N * 4);
  size_t pqh_bytes = (size_t)N * 256 * 2;
  if (off < mark + pqh_bytes) off = mark + ((pqh_bytes + 255) & ~(size_t)255);
  __half* PQh = (__half*)(w + mark);

  hipMemsetAsync(d_out, 0, (size_t)out_size * 4, stream);
  hipMemsetAsync(pos_c, 0, 8, stream);

  k_init<<<(N * 192 + 255) / 256, 256, 0, stream>>>(con, str, Fa, sums, cnt, g, N);
  k_wprep<<<(256 * 128 + 255) / 256, 256, 0, stream>>>(W1, BT);
  k_projm<<<(N + 15) / 16, 256, 0, stream>>>(Fa, BT, b1, PQh, N);
  k_edge<<<(E + 255) / 256, 256, 0, stream>>>(src, dst, PQh, W2, b2, scores, sums, cnt,
                                              pos_s, pos_d, &pos_c[0], bord, &pos_c[1], E);
  k_border<<<512, 256, 0, stream>>>(src, dst, con, W1, b1, W2, b2, bord, &pos_c[1],
                                    scores, sums, cnt, pos_s, pos_d, &pos_c[0]);
  // PQh dead from here; overlap region becomes CSR/compaction storage.
  k_scan_red<<<NB, 1024, 0, stream>>>(0, cnt, g, bsum, N);
  k_scan_mid<<<1, 64, 0, stream>>>(0, bsum, bexcl, NB, rowp, N);
  k_scan_out<<<NB, 1024, 0, stream>>>(0, cnt, g, sums, bexcl, rowp, fillp, colA, wtA, rank, N);
  k_fill<<<(E + 255) / 256, 256, 0, stream>>>(src, dst, scores, sums, fillp, colA, wtA, E);

  __half* fin = Fa; __half* fout = Fb;
  for (int it = 0; it < 5; ++it) {
    k_spmm<<<((size_t)N * 24 + 191) / 192, 192, 0, stream>>>(fin, fout, rowp, colA, wtA, N);
    __half* tmp = fin; fin = fout; fout = tmp;
  }

  for (int r = 0; r < 9; ++r)
    k_prop<<<(E + 255) / 256, 256, 0, stream>>>(pos_s, pos_d, &pos_c[0], g, N);

  k_scan_red<<<NB, 1024, 0, stream>>>(1, cnt, g, bsum, N);
  k_scan_mid<<<1, 64, 0, stream>>>(1, bsum, bexcl, NB, rowp, N);
  k_scan_out<<<NB, 1024, 0, stream>>>(1, cnt, g, sums, bexcl, rowp, fillp, colA, wtA, rank, N);
  hipMemsetAsync(gcnt, 0, (size_t)N * 4, stream);
  k_gcnt<<<(N + 255) / 256, 256, 0, stream>>>(g, rank, gcnt, N);
  k_inv<<<(N + 255) / 256, 256, 0, stream>>>(gcnt, invc, N);
  k_accum<<<(N + 63) / 64, 192, 0, stream>>>(fin, g, rank, invc, (float*)d_out, N);
}